// Round 2
// baseline (658.074 us; speedup 1.0000x reference)
//
#include <hip/hip_runtime.h>

// CAPBlock: q/k shared projection + v projection (GEMMs), L1-distance attention
// logits, rel-attn sigmoid normalize (p=1), PV.
//
// Round-2: workspace-safe. k/v scratch fp16 (32MB), po partials fp16, strict
// ws_size fit with nch*QS=16 grid invariant (512 attn blocks always).
//
// Shapes: B=4, Q=256, K=4096, Ein=E=512, H=8, DH=64.

#define BATCH 4
#define QLEN 256
#define KLEN 4096
#define EDIM 512
#define NHEAD 8
#define DHEAD 64

#define L1_CENTER 72.21632f
#define INV_L1_SCALING (1.0f / 6.8200176f)

typedef _Float16 f16x8 __attribute__((ext_vector_type(8)));
typedef _Float16 f16x4 __attribute__((ext_vector_type(4)));
typedef unsigned short ushort_t;

// ---------------- mask dtype detection (bool-as-byte vs int32) --------------
// int32 0/1 mask => every byte at offset%4!=0 is zero. byte-bool mask =>
// random ones at misaligned offsets. Deterministic function of the input.
__global__ void detect_mask_kernel(const unsigned char* __restrict__ m,
                                   int* __restrict__ flag) {
    __shared__ int nz;
    if (threadIdx.x == 0) nz = 0;
    __syncthreads();
    int acc = 0;
    for (int i = threadIdx.x; i < BATCH * KLEN; i += 256)
        if (i & 3) acc |= m[i];
    if (acc) atomicOr(&nz, 1);
    __syncthreads();
    if (threadIdx.x == 0) *flag = (nz == 0) ? 1 : 0;  // 1 => int32, 0 => byte
}

// ---------------- f32 NT GEMM: C[m][n] = (sum_k A[m][k]*Bw[n][k] + bias[n]) * scale?[n]
#define BM 128
#define BN 64
#define BK 16

template <bool HALF_OUT>
__global__ __launch_bounds__(256) void gemm_nt_kernel(
    const float* __restrict__ A, const float* __restrict__ Bw,
    const float* __restrict__ bias, const float* __restrict__ scale,
    void* __restrict__ Cout, int M) {
    __shared__ float As[BK][BM + 4];
    __shared__ float Bs[BK][BN + 4];

    const int tid = threadIdx.x;
    const int tx = tid & 15;   // n-group: 4 cols each
    const int ty = tid >> 4;   // m-group: 8 rows each
    const int n0 = blockIdx.x * BN;
    const int m0 = blockIdx.y * BM;

    float acc[8][4];
#pragma unroll
    for (int i = 0; i < 8; ++i)
#pragma unroll
        for (int j = 0; j < 4; ++j) acc[i][j] = 0.f;

    const int lrow = tid >> 2;  // 0..63
    const int kp = tid & 3;     // which float4 of the 16-wide k-slab

    for (int k0 = 0; k0 < EDIM; k0 += BK) {
        float4 a0 = *(const float4*)&A[(size_t)(m0 + lrow) * EDIM + k0 + kp * 4];
        float4 a1 = *(const float4*)&A[(size_t)(m0 + 64 + lrow) * EDIM + k0 + kp * 4];
        float4 b0 = *(const float4*)&Bw[(size_t)(n0 + lrow) * EDIM + k0 + kp * 4];
        __syncthreads();  // previous tile fully consumed
        As[kp * 4 + 0][lrow] = a0.x;
        As[kp * 4 + 1][lrow] = a0.y;
        As[kp * 4 + 2][lrow] = a0.z;
        As[kp * 4 + 3][lrow] = a0.w;
        As[kp * 4 + 0][64 + lrow] = a1.x;
        As[kp * 4 + 1][64 + lrow] = a1.y;
        As[kp * 4 + 2][64 + lrow] = a1.z;
        As[kp * 4 + 3][64 + lrow] = a1.w;
        Bs[kp * 4 + 0][lrow] = b0.x;
        Bs[kp * 4 + 1][lrow] = b0.y;
        Bs[kp * 4 + 2][lrow] = b0.z;
        Bs[kp * 4 + 3][lrow] = b0.w;
        __syncthreads();
#pragma unroll
        for (int kk = 0; kk < BK; ++kk) {
            const float4 av0 = *(const float4*)&As[kk][ty * 8];
            const float4 av1 = *(const float4*)&As[kk][ty * 8 + 4];
            const float4 bv = *(const float4*)&Bs[kk][tx * 4];
            const float a[8] = {av0.x, av0.y, av0.z, av0.w, av1.x, av1.y, av1.z, av1.w};
            const float bb[4] = {bv.x, bv.y, bv.z, bv.w};
#pragma unroll
            for (int i = 0; i < 8; ++i)
#pragma unroll
                for (int j = 0; j < 4; ++j) acc[i][j] += a[i] * bb[j];
        }
    }

    const float4 bias4 = *(const float4*)&bias[n0 + tx * 4];
    float4 sc4;
    if (scale) sc4 = *(const float4*)&scale[n0 + tx * 4];
    else { sc4.x = sc4.y = sc4.z = sc4.w = 1.f; }
#pragma unroll
    for (int i = 0; i < 8; ++i) {
        const int m = m0 + ty * 8 + i;
        float4 r;
        r.x = (acc[i][0] + bias4.x) * sc4.x;
        r.y = (acc[i][1] + bias4.y) * sc4.y;
        r.z = (acc[i][2] + bias4.z) * sc4.z;
        r.w = (acc[i][3] + bias4.w) * sc4.w;
        if constexpr (HALF_OUT) {
            f16x4 hh;
            hh[0] = (_Float16)r.x; hh[1] = (_Float16)r.y;
            hh[2] = (_Float16)r.z; hh[3] = (_Float16)r.w;
            *(f16x4*)&((_Float16*)Cout)[(size_t)m * EDIM + n0 + tx * 4] = hh;
        } else {
            *(float4*)&((float*)Cout)[(size_t)m * EDIM + n0 + tx * 4] = r;
        }
    }
}

// ---------------- fused L1-distance attention (partial over a K-chunk) ------
// Grid fixed at (NCH*QS=16, H, B) = 512 blocks. NCH = 16/QS K-chunks; QS
// q-splits per chunk. Block threads = QS ks-groups x QPER q-rows. Each thread
// accumulates s,o over its ks-subset of each 64-row K/V tile; for QS>1 an LDS
// tree reduces over ks-groups at the end. po fp16 d-major, ps f32.
template <int QS>
__global__ __launch_bounds__(256) void attn_kernel(
    const float* __restrict__ qb, const _Float16* __restrict__ kh,
    const _Float16* __restrict__ vh, const void* __restrict__ mask,
    const float* __restrict__ rel, const int* __restrict__ mflag,
    ushort_t* __restrict__ po, float* __restrict__ ps) {
    constexpr int NCH = 16 / QS;
    constexpr int QPER = 256 / QS;     // q rows per block
    constexpr int RPT = 64 / QS;       // K-tile rows per thread
    constexpr int KCHUNK = KLEN / NCH;
    constexpr int NTILES = KCHUNK / 64;

    struct KV { float4 K[64][16]; float4 V[64][16]; };
    __shared__ union U { KV kv; float red[256][65]; } u;
    __shared__ float Ms[64];

    const int tid = threadIdx.x;
    const int c = blockIdx.x % NCH;
    const int qs = blockIdx.x / NCH;
    const int h = blockIdx.y, b = blockIdx.z;
    const int ql = tid % QPER;
    const int ks = tid / QPER;
    const int qg = qs * QPER + ql;     // global q row 0..255
    const int mfl = *mflag;

    float4 qr[16];
#pragma unroll
    for (int d4 = 0; d4 < 16; ++d4)
        qr[d4] = *(const float4*)&qb[((size_t)(b * QLEN + qg)) * EDIM + h * DHEAD + d4 * 4];

    const float adn = rel[b * NHEAD + h];
    float o[64];
#pragma unroll
    for (int d = 0; d < 64; ++d) o[d] = 0.f;
    float s = 0.f;

    for (int t = 0; t < NTILES; ++t) {
        const int kbase = c * KCHUNK + t * 64;
        __syncthreads();  // previous tile fully consumed
#pragma unroll
        for (int p = 0; p < 2; ++p) {
            const int lin = tid + p * 256;
            const int row = lin >> 3, ch = lin & 7;  // 8 halves per chunk
            const size_t g = ((size_t)(b * KLEN + kbase + row)) * EDIM + h * DHEAD + ch * 8;
            const f16x8 k8 = *(const f16x8*)&kh[g];
            const f16x8 v8 = *(const f16x8*)&vh[g];
            float4 klo, khi, vlo, vhi;
            klo.x = (float)k8[0]; klo.y = (float)k8[1]; klo.z = (float)k8[2]; klo.w = (float)k8[3];
            khi.x = (float)k8[4]; khi.y = (float)k8[5]; khi.z = (float)k8[6]; khi.w = (float)k8[7];
            vlo.x = (float)v8[0]; vlo.y = (float)v8[1]; vlo.z = (float)v8[2]; vlo.w = (float)v8[3];
            vhi.x = (float)v8[4]; vhi.y = (float)v8[5]; vhi.z = (float)v8[6]; vhi.w = (float)v8[7];
            u.kv.K[row][ch * 2] = klo;
            u.kv.K[row][ch * 2 + 1] = khi;
            u.kv.V[row][ch * 2] = vlo;
            u.kv.V[row][ch * 2 + 1] = vhi;
        }
        if (tid < 64) {
            const int kg = b * KLEN + kbase + tid;
            const int mv = mfl ? ((const int*)mask)[kg]
                               : (int)((const unsigned char*)mask)[kg];
            Ms[tid] = mv ? 1.0f : 0.0f;
        }
        __syncthreads();

#pragma unroll 2
        for (int r = 0; r < RPT; ++r) {
            const int kk = ks * RPT + r;  // wave-uniform per ks-group
            float a0 = 0.f, a1 = 0.f, a2 = 0.f, a3 = 0.f;
#pragma unroll
            for (int d4 = 0; d4 < 16; ++d4) {
                const float4 kv = u.kv.K[kk][d4];  // broadcast read
                a0 += fabsf(kv.x - qr[d4].x);
                a1 += fabsf(kv.y - qr[d4].y);
                a2 += fabsf(kv.z - qr[d4].z);
                a3 += fabsf(kv.w - qr[d4].w);
            }
            const float unsc = (a0 + a1) + (a2 + a3);
            const float e = Ms[kk] * __expf((L1_CENTER - unsc) * INV_L1_SCALING);
            const float w = e * __builtin_amdgcn_rcpf(e + adn);
            s += w;
#pragma unroll
            for (int d4 = 0; d4 < 16; ++d4) {
                const float4 vv = u.kv.V[kk][d4];
                o[d4 * 4 + 0] += w * vv.x;
                o[d4 * 4 + 1] += w * vv.y;
                o[d4 * 4 + 2] += w * vv.z;
                o[d4 * 4 + 3] += w * vv.w;
            }
        }
    }

    const size_t bhc = (size_t)(b * NHEAD + h) * NCH + c;
    if constexpr (QS == 1) {
        ps[bhc * QLEN + qg] = s;
#pragma unroll
        for (int d = 0; d < 64; ++d) {
            const _Float16 hv = (_Float16)o[d];
            po[(bhc * 64 + d) * QLEN + qg] = *(const ushort_t*)&hv;
        }
    } else {
        __syncthreads();  // all ks-groups done computing from u.kv
        const int rrow = ks * QPER + ql;
        u.red[rrow][0] = s;
#pragma unroll
        for (int d = 0; d < 64; ++d) u.red[rrow][1 + d] = o[d];
        __syncthreads();
        if (ks == 0) {
            float st = 0.f;
#pragma unroll
            for (int k2 = 0; k2 < QS; ++k2) st += u.red[k2 * QPER + ql][0];
            ps[bhc * QLEN + qg] = st;
            for (int d = 0; d < 64; ++d) {
                float ot = 0.f;
#pragma unroll
                for (int k2 = 0; k2 < QS; ++k2) ot += u.red[k2 * QPER + ql][1 + d];
                const _Float16 hv = (_Float16)ot;
                po[(bhc * 64 + d) * QLEN + qg] = *(const ushort_t*)&hv;
            }
        }
    }
}

// ---------------- combine partials, normalize, write out --------------------
// Grid (16 d-groups, H, B) = 512 blocks; thread = q.
__global__ __launch_bounds__(256) void combine_kernel(
    const ushort_t* __restrict__ po, const float* __restrict__ ps,
    float* __restrict__ out, int nch) {
    const int d4 = blockIdx.x, h = blockIdx.y, b = blockIdx.z;
    const int q = threadIdx.x;
    const int bh = b * NHEAD + h;

    float s = 0.f;
    for (int c = 0; c < nch; ++c)
        s += ps[((size_t)(bh * nch + c)) * QLEN + q];

    float o[4] = {0.f, 0.f, 0.f, 0.f};
    for (int c = 0; c < nch; ++c) {
#pragma unroll
        for (int j = 0; j < 4; ++j) {
            const int d = d4 * 4 + j;
            const ushort_t raw = po[((size_t)((bh * nch + c) * 64 + d)) * QLEN + q];
            o[j] += (float)*(const _Float16*)&raw;
        }
    }
    const float inv = 1.0f / fmaxf(s, 1e-12f);
#pragma unroll
    for (int j = 0; j < 4; ++j)
        out[((size_t)(b * QLEN + q)) * EDIM + h * DHEAD + d4 * 4 + j] = o[j] * inv;
}

extern "C" void kernel_launch(void* const* d_in, const int* in_sizes, int n_in,
                              void* d_out, int out_size, void* d_ws, size_t ws_size,
                              hipStream_t stream) {
    const float* query = (const float*)d_in[0];
    const float* bag   = (const float*)d_in[1];
    const void*  mask  = d_in[2];
    const float* rel   = (const float*)d_in[3];
    const float* Wqk   = (const float*)d_in[4];
    const float* bqk   = (const float*)d_in[5];
    const float* Wv    = (const float*)d_in[6];
    const float* bv    = (const float*)d_in[7];
    const float* diag  = (const float*)d_in[8];  // [H*DH] == q/k column order
    float* out = (float*)d_out;

    const size_t fQ = (size_t)BATCH * QLEN * EDIM;   // 524288 f32
    const size_t fK = (size_t)BATCH * KLEN * EDIM;   // 8388608 halves each
    const size_t poEls1 = (size_t)BATCH * NHEAD * QLEN * DHEAD;  // per chunk
    const size_t psEls1 = (size_t)BATCH * NHEAD * QLEN;

    // strict-fit chunk count; nch*QS = 16 keeps attn grid at 512 blocks
    int nch = 16;
    while (nch > 1) {
        const size_t need = 16 + fQ * 4 + fK * 2 * 2 +
                            poEls1 * nch * 2 + psEls1 * nch * 4;
        if (need <= ws_size) break;
        nch >>= 1;
    }

    char* wsb = (char*)d_ws;
    int* mflag = (int*)wsb;
    float* qbuf = (float*)(wsb + 16);
    _Float16* kh = (_Float16*)(wsb + 16 + fQ * 4);
    _Float16* vh = kh + fK;
    ushort_t* po = (ushort_t*)(vh + fK);
    float* psb = (float*)(po + poEls1 * nch);

    detect_mask_kernel<<<1, 256, 0, stream>>>((const unsigned char*)mask, mflag);

    // q' = (query@Wqk^T + bqk)*diag (f32); k' likewise (fp16); v = bag@Wv^T+bv (fp16)
    gemm_nt_kernel<false><<<dim3(EDIM / BN, (BATCH * QLEN) / BM), 256, 0, stream>>>(
        query, Wqk, bqk, diag, qbuf, BATCH * QLEN);
    gemm_nt_kernel<true><<<dim3(EDIM / BN, (BATCH * KLEN) / BM), 256, 0, stream>>>(
        bag, Wqk, bqk, diag, kh, BATCH * KLEN);
    gemm_nt_kernel<true><<<dim3(EDIM / BN, (BATCH * KLEN) / BM), 256, 0, stream>>>(
        bag, Wv, bv, nullptr, vh, BATCH * KLEN);

    const dim3 agrid(16, NHEAD, BATCH);  // nch*QS = 16 always
    switch (nch) {
        case 16: attn_kernel<1><<<agrid, 256, 0, stream>>>(qbuf, kh, vh, mask, rel, mflag, po, psb); break;
        case 8:  attn_kernel<2><<<agrid, 256, 0, stream>>>(qbuf, kh, vh, mask, rel, mflag, po, psb); break;
        case 4:  attn_kernel<4><<<agrid, 256, 0, stream>>>(qbuf, kh, vh, mask, rel, mflag, po, psb); break;
        case 2:  attn_kernel<8><<<agrid, 256, 0, stream>>>(qbuf, kh, vh, mask, rel, mflag, po, psb); break;
        default: attn_kernel<16><<<agrid, 256, 0, stream>>>(qbuf, kh, vh, mask, rel, mflag, po, psb); break;
    }

    combine_kernel<<<dim3(16, NHEAD, BATCH), 256, 0, stream>>>(po, psb, out, nch);
}

// Round 3
// 231.522 us; speedup vs baseline: 2.8424x; 2.8424x over previous
//
#include <hip/hip_runtime.h>

// CAPBlock r3: fp16 MFMA projections + MFMA-PV L1-distance attention.
// Shapes: B=4, Q=256, K=4096, Ein=E=512, H=8, DH=64.
//
// ws (43.2MB): mflag(16B) | qh fp16 1MB | kh fp16 16.8MB | vT fp16 16.8MB
//              | po fp16 8.4MB | ps f32 0.26MB   (round-2 proved ws >= 54MB)

#define BATCH 4
#define QLEN 256
#define KLEN 4096
#define EDIM 512
#define NHEAD 8
#define DHEAD 64
#define NC 8  // k-chunks for attention partials

#define L1_CENTER 72.21632f
#define INV_L1_SCALING (1.0f / 6.8200176f)

typedef float f32x4 __attribute__((ext_vector_type(4)));
typedef _Float16 f16x8 __attribute__((ext_vector_type(8)));
typedef _Float16 f16x4 __attribute__((ext_vector_type(4)));
typedef _Float16 h2 __attribute__((ext_vector_type(2)));
typedef unsigned int u32x4 __attribute__((ext_vector_type(4)));

// ---------------- mask dtype detection (bool-as-byte vs int32) --------------
__global__ void detect_mask_kernel(const unsigned char* __restrict__ m,
                                   int* __restrict__ flag) {
    __shared__ int nz;
    if (threadIdx.x == 0) nz = 0;
    __syncthreads();
    int acc = 0;
    for (int i = threadIdx.x; i < BATCH * KLEN; i += 256)
        if (i & 3) acc |= m[i];
    if (acc) atomicOr(&nz, 1);
    __syncthreads();
    if (threadIdx.x == 0) *flag = (nz == 0) ? 1 : 0;  // 1 => int32, 0 => byte
}

// ---------------- fp16 MFMA NT GEMM ----------------------------------------
// C[m][n] = sum_k A[m][k]*W[n][k] (+bias[n]) (*scale[n]); A,W f32 in HBM,
// cvt to fp16 (RNE) while staging. 128x128 tile, BK=32, 4 waves (2x2),
// each wave 64x64 = 4x4 frags of mfma_f32_16x16x32_f16.
// OUTM=0: fp16 row-major out, value (acc+bias)*scale.
// OUTM=1: out = vT[(b*8+h)*64+d][k] transposed fp16, value acc+bias.
template <int OUTM>
__global__ __launch_bounds__(256) void gemm_f16_mfma(
    const float* __restrict__ A, const float* __restrict__ W,
    const float* __restrict__ bias, const float* __restrict__ scale,
    _Float16* __restrict__ C) {
    __shared__ _Float16 As[128][40];  // +8 halves pad: 2-way banks, 16B-aligned
    __shared__ _Float16 Bs[128][40];

    const int tid = threadIdx.x;
    const int lane = tid & 63, wid = tid >> 6;
    const int wm = wid >> 1, wn = wid & 1;
    const int l15 = lane & 15, kg4 = lane >> 4;
    const int n0 = blockIdx.x * 128, m0 = blockIdx.y * 128;

    f32x4 acc[4][4];
#pragma unroll
    for (int i = 0; i < 4; ++i)
#pragma unroll
        for (int j = 0; j < 4; ++j) acc[i][j] = (f32x4)0.f;

    const int r = tid >> 1, hk = tid & 1;  // staging: row, 16-wide k-half

    for (int k0 = 0; k0 < EDIM; k0 += 32) {
        float4 av[4], wv[4];
#pragma unroll
        for (int i = 0; i < 4; ++i) {
            av[i] = *(const float4*)&A[(size_t)(m0 + r) * EDIM + k0 + hk * 16 + i * 4];
            wv[i] = *(const float4*)&W[(size_t)(n0 + r) * EDIM + k0 + hk * 16 + i * 4];
        }
        __syncthreads();  // previous tile consumed
        f16x8 ha0, ha1, hb0, hb1;
#pragma unroll
        for (int i = 0; i < 4; ++i) {  // RNE element casts
            const float* af = (const float*)&av[i];
            const float* wf = (const float*)&wv[i];
            if (i < 2) {
#pragma unroll
                for (int j = 0; j < 4; ++j) { ha0[i * 4 + j] = (_Float16)af[j]; hb0[i * 4 + j] = (_Float16)wf[j]; }
            } else {
#pragma unroll
                for (int j = 0; j < 4; ++j) { ha1[(i - 2) * 4 + j] = (_Float16)af[j]; hb1[(i - 2) * 4 + j] = (_Float16)wf[j]; }
            }
        }
        *(f16x8*)&As[r][hk * 16] = ha0;
        *(f16x8*)&As[r][hk * 16 + 8] = ha1;
        *(f16x8*)&Bs[r][hk * 16] = hb0;
        *(f16x8*)&Bs[r][hk * 16 + 8] = hb1;
        __syncthreads();

        f16x8 a8[4];
#pragma unroll
        for (int mf = 0; mf < 4; ++mf)
            a8[mf] = *(const f16x8*)&As[wm * 64 + mf * 16 + l15][kg4 * 8];
#pragma unroll
        for (int nf = 0; nf < 4; ++nf) {
            const f16x8 b8 = *(const f16x8*)&Bs[wn * 64 + nf * 16 + l15][kg4 * 8];
#pragma unroll
            for (int mf = 0; mf < 4; ++mf)
                acc[mf][nf] = __builtin_amdgcn_mfma_f32_16x16x32_f16(a8[mf], b8, acc[mf][nf], 0, 0, 0);
        }
    }

#pragma unroll
    for (int nf = 0; nf < 4; ++nf) {
        const int n = n0 + wn * 64 + nf * 16 + l15;
        const float bi = bias[n];
        if constexpr (OUTM == 0) {
            const float sc = scale ? scale[n] : 1.f;
#pragma unroll
            for (int mf = 0; mf < 4; ++mf)
#pragma unroll
                for (int rr = 0; rr < 4; ++rr) {
                    const int m = m0 + wm * 64 + mf * 16 + kg4 * 4 + rr;
                    C[(size_t)m * EDIM + n] = (_Float16)((acc[mf][nf][rr] + bi) * sc);
                }
        } else {
#pragma unroll
            for (int mf = 0; mf < 4; ++mf) {
                const int kb = m0 + wm * 64 + mf * 16 + kg4 * 4;  // global m
                const int bb = kb >> 12, kk = kb & (KLEN - 1);    // batch, k
                f16x4 pk;
#pragma unroll
                for (int rr = 0; rr < 4; ++rr) pk[rr] = (_Float16)(acc[mf][nf][rr] + bi);
                *(f16x4*)&C[((size_t)(bb * NHEAD + (n >> 6)) * DHEAD + (n & 63)) * KLEN + kk] = pk;
            }
        }
    }
}

// ---------------- L1-distance attention, MFMA PV ----------------------------
// grid (NC*2, H, B); block = 4 waves x 32 q = 128 q-rows (q-half qhi),
// k-chunk of 512. Lane l: q-subtiles s in {0,1} -> q = s*16+(l&15);
// k-set = (l>>4)*8 + j within each 32-k MFMA tile (= A-frag layout).
__device__ __forceinline__ float l1acc(unsigned ku, unsigned qu, float acc) {
    const h2 d = __builtin_bit_cast(h2, ku) - __builtin_bit_cast(h2, qu);
    const unsigned du = __builtin_bit_cast(unsigned, d) & 0x7fff7fffu;
    const h2 one2 = {(_Float16)1.f, (_Float16)1.f};
    return __builtin_amdgcn_fdot2(__builtin_bit_cast(h2, du), one2, acc, false);
}

__global__ __launch_bounds__(256) void attn_mfma_kernel(
    const _Float16* __restrict__ qh, const _Float16* __restrict__ kh,
    const _Float16* __restrict__ vT, const void* __restrict__ mask,
    const float* __restrict__ rel, const int* __restrict__ mflag,
    unsigned short* __restrict__ po, float* __restrict__ ps) {
    __shared__ union SM {
        struct { _Float16 K[64][64]; _Float16 V[64][72]; _Float16 M[64]; } t;
        _Float16 osm[64][136];  // epilogue d x q transpose buffer
    } sm;

    const int tid = threadIdx.x;
    const int lane = tid & 63, wid = tid >> 6;
    const int l15 = lane & 15, kg4 = lane >> 4;
    const int c = blockIdx.x & (NC - 1), qhi = blockIdx.x / NC;
    const int h = blockIdx.y, b = blockIdx.z;
    const int qbase = qhi * 128 + wid * 32;
    const int mfl = *mflag;
    const float adn = rel[b * NHEAD + h];

    // q fragments: 2 subtiles x 8 chunks x 4 packed pairs
    unsigned qreg[2][32];
#pragma unroll
    for (int s = 0; s < 2; ++s) {
        const int qrow = b * QLEN + qbase + s * 16 + l15;
#pragma unroll
        for (int c8 = 0; c8 < 8; ++c8) {
            const f16x8 v = *(const f16x8*)&qh[(size_t)qrow * EDIM + h * DHEAD + c8 * 8];
            const u32x4 u = __builtin_bit_cast(u32x4, v);
#pragma unroll
            for (int p = 0; p < 4; ++p) qreg[s][c8 * 4 + p] = u[p];
        }
    }

    f32x4 acc[2][4];
#pragma unroll
    for (int s = 0; s < 2; ++s)
#pragma unroll
        for (int nf = 0; nf < 4; ++nf) acc[s][nf] = (f32x4)0.f;
    float sacc[2] = {0.f, 0.f};

    const int kc0 = c * (KLEN / NC);
    for (int t = 0; t < (KLEN / NC) / 64; ++t) {
        const int kbase = kc0 + t * 64;
        __syncthreads();  // previous tile consumed
        {
            const int rr = tid >> 2, c0 = (tid & 3) * 2;
            // K: row-major [64][64] fp16, chunk-XOR-swizzled (4 broadcast groups
            // land on distinct banks on the read side)
            const f16x8* gk = (const f16x8*)&kh[((size_t)(b * KLEN + kbase + rr)) * EDIM + h * DHEAD + c0 * 8];
            const int sw = (rr >> 3) & 7;
            *(f16x8*)&sm.t.K[rr][((c0) ^ sw) * 8] = gk[0];
            *(f16x8*)&sm.t.K[rr][((c0 + 1) ^ sw) * 8] = gk[1];
            // Vt: [64 d][64 k] fp16, rows padded to 72 halves (2-way banks)
            const f16x8* gv = (const f16x8*)&vT[((size_t)((b * NHEAD + h) * DHEAD + rr)) * KLEN + kbase + c0 * 8];
            *(f16x8*)&sm.t.V[rr][c0 * 8] = gv[0];
            *(f16x8*)&sm.t.V[rr][c0 * 8 + 8] = gv[1];
            if (tid < 64) {
                const int kg = b * KLEN + kbase + tid;
                const int mv = mfl ? ((const int*)mask)[kg]
                                   : (int)((const unsigned char*)mask)[kg];
                sm.t.M[tid] = mv ? (_Float16)1.f : (_Float16)0.f;
            }
        }
        __syncthreads();

#pragma unroll
        for (int hf = 0; hf < 2; ++hf) {  // two 32-k MFMA tiles
            const int kl0 = hf * 32 + kg4 * 8;
            float dist[2][8];
#pragma unroll
            for (int s = 0; s < 2; ++s)
#pragma unroll
                for (int j = 0; j < 8; ++j) dist[s][j] = 0.f;

#pragma unroll
            for (int j = 0; j < 8; ++j) {
                const int kk = kl0 + j;
                const int sw = (kk >> 3) & 7;
#pragma unroll
                for (int c8 = 0; c8 < 8; ++c8) {
                    const f16x8 kv = *(const f16x8*)&sm.t.K[kk][(c8 ^ sw) * 8];
                    const u32x4 ku = __builtin_bit_cast(u32x4, kv);
#pragma unroll
                    for (int p = 0; p < 4; ++p) {
                        dist[0][j] = l1acc(ku[p], qreg[0][c8 * 4 + p], dist[0][j]);
                        dist[1][j] = l1acc(ku[p], qreg[1][c8 * 4 + p], dist[1][j]);
                    }
                }
            }

            const f16x8 mv8 = *(const f16x8*)&sm.t.M[kl0];
            unsigned pw[2][4];
#pragma unroll
            for (int s = 0; s < 2; ++s) {
                float w[8];
#pragma unroll
                for (int j = 0; j < 8; ++j) {
                    // e = mask * exp((C-dist)/S); w = e/(e+adn)  (== reference)
                    const float e = __expf((L1_CENTER - dist[s][j]) * INV_L1_SCALING) * (float)mv8[j];
                    w[j] = e * __builtin_amdgcn_rcpf(e + adn);
                    sacc[s] += w[j];
                }
#pragma unroll
                for (int m2 = 0; m2 < 4; ++m2)
                    pw[s][m2] = __builtin_bit_cast(unsigned,
                        __builtin_amdgcn_cvt_pkrtz(w[2 * m2], w[2 * m2 + 1]));
            }

#pragma unroll
            for (int nf = 0; nf < 4; ++nf) {
                const f16x8 b8 = *(const f16x8*)&sm.t.V[nf * 16 + l15][hf * 32 + kg4 * 8];
                union { unsigned u[4]; f16x8 v; } a0, a1;
#pragma unroll
                for (int p = 0; p < 4; ++p) { a0.u[p] = pw[0][p]; a1.u[p] = pw[1][p]; }
                acc[0][nf] = __builtin_amdgcn_mfma_f32_16x16x32_f16(a0.v, b8, acc[0][nf], 0, 0, 0);
                acc[1][nf] = __builtin_amdgcn_mfma_f32_16x16x32_f16(a1.v, b8, acc[1][nf], 0, 0, 0);
            }
        }
    }

    // s: reduce the 4 k-lane-groups -> full row sums
#pragma unroll
    for (int s = 0; s < 2; ++s) {
        sacc[s] += __shfl_xor(sacc[s], 16);
        sacc[s] += __shfl_xor(sacc[s], 32);
    }
    const size_t bhc = (size_t)(b * NHEAD + h) * NC + c;
    if (lane < 16) {
#pragma unroll
        for (int s = 0; s < 2; ++s)
            ps[bhc * QLEN + qbase + s * 16 + lane] = sacc[s];
    }

    // po: stage C-frags into LDS [d][q] then store coalesced (fp16, d-major)
    __syncthreads();  // everyone done with sm.t
#pragma unroll
    for (int s = 0; s < 2; ++s)
#pragma unroll
        for (int nf = 0; nf < 4; ++nf)
#pragma unroll
            for (int rr = 0; rr < 4; ++rr) {
                const int qloc = wid * 32 + s * 16 + kg4 * 4 + rr;
                sm.osm[nf * 16 + l15][qloc] = (_Float16)acc[s][nf][rr];
            }
    __syncthreads();
    {
        const int d = tid >> 2, seg = tid & 3;
        const f16x8* src = (const f16x8*)&sm.osm[d][seg * 32];
        f16x8* dst = (f16x8*)(po + (bhc * 64 + d) * QLEN + qhi * 128 + seg * 32);
#pragma unroll
        for (int i = 0; i < 4; ++i) dst[i] = src[i];
    }
}

// ---------------- combine partials, normalize, write out --------------------
__global__ __launch_bounds__(256) void combine_kernel(
    const unsigned short* __restrict__ po, const float* __restrict__ ps,
    float* __restrict__ out, int nch) {
    const int d4 = blockIdx.x, h = blockIdx.y, b = blockIdx.z;
    const int q = threadIdx.x;
    const int bh = b * NHEAD + h;

    float s = 0.f;
    for (int c = 0; c < nch; ++c)
        s += ps[((size_t)(bh * nch + c)) * QLEN + q];

    float o[4] = {0.f, 0.f, 0.f, 0.f};
    for (int c = 0; c < nch; ++c) {
#pragma unroll
        for (int j = 0; j < 4; ++j) {
            const int d = d4 * 4 + j;
            const unsigned short raw = po[((size_t)((bh * nch + c) * 64 + d)) * QLEN + q];
            o[j] += (float)*(const _Float16*)&raw;
        }
    }
    const float inv = 1.0f / fmaxf(s, 1e-12f);
#pragma unroll
    for (int j = 0; j < 4; ++j)
        out[((size_t)(b * QLEN + q)) * EDIM + h * DHEAD + d4 * 4 + j] = o[j] * inv;
}

extern "C" void kernel_launch(void* const* d_in, const int* in_sizes, int n_in,
                              void* d_out, int out_size, void* d_ws, size_t ws_size,
                              hipStream_t stream) {
    const float* query = (const float*)d_in[0];
    const float* bag   = (const float*)d_in[1];
    const void*  mask  = d_in[2];
    const float* rel   = (const float*)d_in[3];
    const float* Wqk   = (const float*)d_in[4];
    const float* bqk   = (const float*)d_in[5];
    const float* Wv    = (const float*)d_in[6];
    const float* bv    = (const float*)d_in[7];
    const float* diag  = (const float*)d_in[8];  // [H*DH] == q/k column order
    float* out = (float*)d_out;

    char* wsb = (char*)d_ws;
    int* mflag = (int*)wsb;
    _Float16* qh = (_Float16*)(wsb + 16);
    _Float16* kh = qh + (size_t)BATCH * QLEN * EDIM;
    _Float16* vT = kh + (size_t)BATCH * KLEN * EDIM;
    unsigned short* po = (unsigned short*)(vT + (size_t)BATCH * KLEN * EDIM);
    float* psb = (float*)(po + (size_t)BATCH * NHEAD * NC * QLEN * DHEAD);

    detect_mask_kernel<<<1, 256, 0, stream>>>((const unsigned char*)mask, mflag);

    // q' = (query@Wqk^T + bqk)*diag ; k' likewise ; v = bag@Wv^T + bv (-> vT)
    gemm_f16_mfma<0><<<dim3(EDIM / 128, (BATCH * QLEN) / 128), 256, 0, stream>>>(
        query, Wqk, bqk, diag, qh);
    gemm_f16_mfma<0><<<dim3(EDIM / 128, (BATCH * KLEN) / 128), 256, 0, stream>>>(
        bag, Wqk, bqk, diag, kh);
    gemm_f16_mfma<1><<<dim3(EDIM / 128, (BATCH * KLEN) / 128), 256, 0, stream>>>(
        bag, Wv, bv, nullptr, vT);

    attn_mfma_kernel<<<dim3(NC * 2, NHEAD, BATCH), 256, 0, stream>>>(
        qh, kh, vT, mask, rel, mflag, po, psb);

    combine_kernel<<<dim3(16, NHEAD, BATCH), 256, 0, stream>>>(po, psb, out, NC);
}